// Round 4
// baseline (367.423 us; speedup 1.0000x reference)
//
#include <hip/hip_runtime.h>
#include <hip/hip_cooperative_groups.h>

namespace cg = cooperative_groups;

#define C_DIM 512
#define G_DIM 128
#define ROW_STRIDE 1536   // 3*C
#define NBLOCKS 2048      // 8 blocks/CU on 256 CUs (co-resident via launch_bounds)
#define NTHREADS 128
#define MAX_ROWS 64       // ceil(100000/2048)=49 <= 64
#define CHUNK 8

// Order-preserving float->uint mapping (monotonic for all finite floats,
// negatives map below positives). Key 0 is below enc(-inf), safe init.
__device__ __forceinline__ unsigned enc_f32(float f) {
    unsigned b = __float_as_uint(f);
    return (b & 0x80000000u) ? ~b : (b | 0x80000000u);
}
__device__ __forceinline__ float dec_f32(unsigned k) {
    unsigned b = (k & 0x80000000u) ? (k ^ 0x80000000u) : ~k;
    return __uint_as_float(b);
}

__device__ __forceinline__ void flush_seg(float* __restrict__ out, int g, int c0,
                                          const float4& s, const float4& m,
                                          int run_len, int tid) {
    float* so = out + (size_t)g * ROW_STRIDE + 1024 + c0;
    atomicAdd(so + 0, s.x);
    atomicAdd(so + 1, s.y);
    atomicAdd(so + 2, s.z);
    atomicAdd(so + 3, s.w);
    unsigned* mo = reinterpret_cast<unsigned*>(out + (size_t)g * ROW_STRIDE + 512 + c0);
    atomicMax(mo + 0, enc_f32(m.x));
    atomicMax(mo + 1, enc_f32(m.y));
    atomicMax(mo + 2, enc_f32(m.z));
    atomicMax(mo + 3, enc_f32(m.w));
    if (tid == 0) {  // count lives in the mean region, col 0 (read before overwrite)
        atomicAdd(reinterpret_cast<int*>(out) + (size_t)g * ROW_STRIDE, run_len);
    }
}

__device__ __forceinline__ void acc4(float4& s, float4& m, const float4& v) {
    s.x += v.x; s.y += v.y; s.z += v.z; s.w += v.w;
    m.x = fmaxf(m.x, v.x); m.y = fmaxf(m.y, v.y);
    m.z = fmaxf(m.z, v.z); m.w = fmaxf(m.w, v.w);
}

__device__ void pool_body(const float* __restrict__ x, const int* __restrict__ batch,
                          float* __restrict__ out, int N, int bid, int tid, int nblocks) {
    const int c0 = tid * 4;                 // 128 threads * 4 ch = 512 channels
    const int r0 = (int)((long long)bid * N / nblocks);
    const int r1 = (int)((long long)(bid + 1) * N / nblocks);
    const int nrows = r1 - r0;
    if (nrows <= 0) return;

    const int gfirst = batch[r0];
    const int glast  = batch[r1 - 1];

    if (gfirst == glast) {
        // ---- Fast path (~94% of blocks): whole range is one segment. ----
        // Branch-free streaming loop: no LDS, no atomics, no boundary checks
        // inside -> compiler can keep loads of chunk k+1 in flight during
        // accumulation of chunk k.
        float4 s = make_float4(0.f, 0.f, 0.f, 0.f);
        float4 m = make_float4(-INFINITY, -INFINITY, -INFINITY, -INFINITY);
        const float* base = x + (size_t)r0 * C_DIM + c0;
        int r = 0;
        for (; r + CHUNK <= nrows; r += CHUNK) {
            float4 v[CHUNK];
#pragma unroll
            for (int j = 0; j < CHUNK; ++j)
                v[j] = *reinterpret_cast<const float4*>(base + (size_t)(r + j) * C_DIM);
#pragma unroll
            for (int j = 0; j < CHUNK; ++j) acc4(s, m, v[j]);
        }
        for (; r < nrows; ++r)
            acc4(s, m, *reinterpret_cast<const float4*>(base + (size_t)r * C_DIM));
        flush_seg(out, gfirst, c0, s, m, nrows, tid);
    } else {
        // ---- Slow path: block spans >=1 segment boundary. Chunked scan. ----
        __shared__ int sb[MAX_ROWS];
        if (tid < nrows) sb[tid] = batch[r0 + tid];
        __syncthreads();

        float4 s = make_float4(0.f, 0.f, 0.f, 0.f);
        float4 m = make_float4(-INFINITY, -INFINITY, -INFINITY, -INFINITY);
        int cur = sb[0];
        int run_start = 0;

        int r = 0;
        while (r < nrows) {
            if (nrows - r >= CHUNK && sb[r + CHUNK - 1] == cur) {
                const float* base = x + (size_t)(r0 + r) * C_DIM + c0;
                float4 v[CHUNK];
#pragma unroll
                for (int j = 0; j < CHUNK; ++j)
                    v[j] = *reinterpret_cast<const float4*>(base + (size_t)j * C_DIM);
#pragma unroll
                for (int j = 0; j < CHUNK; ++j) acc4(s, m, v[j]);
                r += CHUNK;
            } else {
                const int rend = min(r + CHUNK, nrows);
                for (; r < rend; ++r) {
                    const int g = sb[r];
                    if (g != cur) {
                        flush_seg(out, cur, c0, s, m, r - run_start, tid);
                        s = make_float4(0.f, 0.f, 0.f, 0.f);
                        m = make_float4(-INFINITY, -INFINITY, -INFINITY, -INFINITY);
                        cur = g;
                        run_start = r;
                    }
                    acc4(s, m, *reinterpret_cast<const float4*>(
                        x + (size_t)(r0 + r) * C_DIM + c0));
                }
            }
        }
        flush_seg(out, cur, c0, s, m, nrows - run_start, tid);
    }
}

__device__ void finalize_body(float* __restrict__ out, int g, int tid) {
    float* row = out + (size_t)g * ROW_STRIDE;
    const int cnt = reinterpret_cast<const int*>(row)[0];
    __syncthreads();   // everyone reads count before tid0 overwrites row[0]
    const float inv = 1.0f / (float)max(cnt, 1);
    for (int c = tid; c < C_DIM; c += NTHREADS) {
        const float sum = row[1024 + c];
        const unsigned k = __float_as_uint(row[512 + c]);
        const float mx = (cnt > 0) ? dec_f32(k) : 0.0f;
        row[c] = sum * inv;     // mean
        row[512 + c] = mx;      // decoded max
        // row[1024 + c] already holds the sum
    }
}

// ---------------- single fused cooperative kernel ----------------
__global__ __launch_bounds__(NTHREADS, 4) void fused_pool_kernel(
        const float* __restrict__ x, const int* __restrict__ batch,
        float* __restrict__ out, int N) {
    cg::grid_group grid = cg::this_grid();
    const int tid = threadIdx.x;
    const int bid = blockIdx.x;

    // phase 0: zero the accumulator region (replaces hipMemsetAsync node)
    for (int i = bid * NTHREADS + tid; i < G_DIM * ROW_STRIDE; i += NBLOCKS * NTHREADS)
        out[i] = 0.0f;
    grid.sync();

    // phase 1: pool
    pool_body(x, batch, out, N, bid, tid, NBLOCKS);
    grid.sync();

    // phase 2: finalize
    if (bid < G_DIM) finalize_body(out, bid, tid);
}

// ---------------- fallback path (3 dispatches) ----------------
__global__ __launch_bounds__(NTHREADS) void pool_kernel(const float* __restrict__ x,
                                                        const int* __restrict__ batch,
                                                        float* __restrict__ out, int N) {
    pool_body(x, batch, out, N, blockIdx.x, threadIdx.x, NBLOCKS);
}

__global__ __launch_bounds__(NTHREADS) void finalize_kernel(float* __restrict__ out) {
    finalize_body(out, blockIdx.x, threadIdx.x);
}

extern "C" void kernel_launch(void* const* d_in, const int* in_sizes, int n_in,
                              void* d_out, int out_size, void* d_ws, size_t ws_size,
                              hipStream_t stream) {
    const float* x     = (const float*)d_in[0];
    const int*   batch = (const int*)d_in[1];
    float* out = (float*)d_out;
    int N = in_sizes[0] / C_DIM;

    void* args[] = { (void*)&x, (void*)&batch, (void*)&out, (void*)&N };
    hipError_t err = hipLaunchCooperativeKernel(
        (const void*)fused_pool_kernel, dim3(NBLOCKS), dim3(NTHREADS),
        args, 0, stream);

    if (err != hipSuccess) {
        // Fallback: classic 3-node path.
        hipMemsetAsync(d_out, 0, (size_t)out_size * sizeof(float), stream);
        pool_kernel<<<NBLOCKS, NTHREADS, 0, stream>>>(x, batch, out, N);
        finalize_kernel<<<G_DIM, NTHREADS, 0, stream>>>(out);
    }
}

// Round 5
// 39.920 us; speedup vs baseline: 9.2040x; 9.2040x over previous
//
#include <hip/hip_runtime.h>

#define C_DIM 512
#define G_DIM 128
#define ROW_STRIDE 1536   // 3*C
#define CGROUPS 8         // channel slices of 64 channels -> grid = 128*8 = 1024 blocks
#define NTHREADS 256      // 16 channel-threads (x float4 = 64ch) x 16 row-replicas
#define RG 16             // row replicas per block

__device__ __forceinline__ int lower_bound(const int* __restrict__ a, int n, int v) {
    int lo = 0, hi = n;
    while (lo < hi) {                 // 17 uniform probes; upper levels shared
        int mid = (lo + hi) >> 1;     // across all blocks -> L2-broadcast-hot
        if (a[mid] < v) lo = mid + 1; else hi = mid;
    }
    return lo;
}

__device__ __forceinline__ void acc4(float4& s, float4& m, const float4& v) {
    s.x += v.x; s.y += v.y; s.z += v.z; s.w += v.w;
    m.x = fmaxf(m.x, v.x); m.y = fmaxf(m.y, v.y);
    m.z = fmaxf(m.z, v.z); m.w = fmaxf(m.w, v.w);
}

// One block owns output row g, channels [cb*64, cb*64+64). It finds its
// segment by binary search (sorted batch), streams the rows branch-free,
// reduces across the 16 row-replicas in LDS, and writes mean/max/sum once.
// No atomics, no zero-init, no finalize pass, single dispatch.
__global__ __launch_bounds__(NTHREADS) void pool_owner_kernel(
        const float* __restrict__ x, const int* __restrict__ batch,
        float* __restrict__ out, int N) {
    const int g   = blockIdx.x >> 3;   // / CGROUPS
    const int cb  = blockIdx.x & 7;    // % CGROUPS
    const int tid = threadIdx.x;
    const int cg  = tid & 15;          // channel thread: owns 4 floats
    const int rg  = tid >> 4;          // row replica 0..15

    const int start = lower_bound(batch, N, g);
    const int end   = lower_bound(batch, N, g + 1);
    const int cnt   = end - start;

    float4 s = make_float4(0.f, 0.f, 0.f, 0.f);
    float4 m = make_float4(-INFINITY, -INFINITY, -INFINITY, -INFINITY);

    const float* base = x + (size_t)start * C_DIM + cb * 64 + cg * 4;

    // Branch-free streaming: rows rg, rg+16, rg+32, ... ; unroll 4 keeps
    // 4 independent float4 loads in flight per thread.
    int r = rg;
    for (; r + 3 * RG < cnt; r += 4 * RG) {
        float4 v0 = *reinterpret_cast<const float4*>(base + (size_t)(r         ) * C_DIM);
        float4 v1 = *reinterpret_cast<const float4*>(base + (size_t)(r +     RG) * C_DIM);
        float4 v2 = *reinterpret_cast<const float4*>(base + (size_t)(r + 2 * RG) * C_DIM);
        float4 v3 = *reinterpret_cast<const float4*>(base + (size_t)(r + 3 * RG) * C_DIM);
        acc4(s, m, v0); acc4(s, m, v1); acc4(s, m, v2); acc4(s, m, v3);
    }
    for (; r < cnt; r += RG)
        acc4(s, m, *reinterpret_cast<const float4*>(base + (size_t)r * C_DIM));

    // Reduce across the 16 row replicas in LDS (tree, conflict-free).
    __shared__ float4 ls[2][RG][16];   // [sum|max][rg][cg] = 8 KB
    ls[0][rg][cg] = s;
    ls[1][rg][cg] = m;
    __syncthreads();
#pragma unroll
    for (int off = RG / 2; off >= 1; off >>= 1) {
        if (rg < off) {
            float4 sa = ls[0][rg][cg], s2 = ls[0][rg + off][cg];
            float4 ma = ls[1][rg][cg], m2 = ls[1][rg + off][cg];
            sa.x += s2.x; sa.y += s2.y; sa.z += s2.z; sa.w += s2.w;
            ma.x = fmaxf(ma.x, m2.x); ma.y = fmaxf(ma.y, m2.y);
            ma.z = fmaxf(ma.z, m2.z); ma.w = fmaxf(ma.w, m2.w);
            ls[0][rg][cg] = sa;
            ls[1][rg][cg] = ma;
        }
        __syncthreads();
    }

    if (rg == 0) {
        float4 fs = ls[0][0][cg];
        float4 fm = ls[1][0][cg];
        const float inv = 1.0f / (float)max(cnt, 1);
        if (cnt == 0) fm = make_float4(0.f, 0.f, 0.f, 0.f);  // torch_geometric: 0 for empty
        float4 mean = make_float4(fs.x * inv, fs.y * inv, fs.z * inv, fs.w * inv);
        float* row = out + (size_t)g * ROW_STRIDE + cb * 64 + cg * 4;
        *reinterpret_cast<float4*>(row)        = mean;
        *reinterpret_cast<float4*>(row + 512)  = fm;
        *reinterpret_cast<float4*>(row + 1024) = fs;
    }
}

extern "C" void kernel_launch(void* const* d_in, const int* in_sizes, int n_in,
                              void* d_out, int out_size, void* d_ws, size_t ws_size,
                              hipStream_t stream) {
    const float* x     = (const float*)d_in[0];
    const int*   batch = (const int*)d_in[1];
    float* out = (float*)d_out;
    int N = in_sizes[0] / C_DIM;

    pool_owner_kernel<<<G_DIM * CGROUPS, NTHREADS, 0, stream>>>(x, batch, out, N);
}